// Round 1
// baseline (1241.781 us; speedup 1.0000x reference)
//
#include <hip/hip_runtime.h>

#define NPIX 256
#define N2   65536
#define FW   768

// ---------------- workspace layout (float offsets) ----------------
#define WS_CHARGE   0
#define WS_ILLUM    (N2)              // downsampled illum (sum of sens*illum/8)
#define WS_SENS     (2*N2)            // downsampled sensitivity (mean)
#define WS_FEAT1    (3*N2)            // 32 x 256 x 256, CHW
#define WS_FEAT2    (WS_FEAT1 + 32*N2)
#define WS_S        (WS_FEAT2 + 32*N2)   // 9 planes of 256x256
#define WS_W1T      (WS_S + 9*N2)        // w1 transposed [k][co]   (9*32)
#define WS_W2T      (WS_W1T + 288)       // w2 transposed [ci*9+k][co] (288*32)
#define WS_W3T      (WS_W2T + 9216)      // w3 transposed [ci*9+k][co] (288*12)
#define WS_SUMS     (WS_W3T + 3456)      // 9 charge sums
#define WS_MEANB    (WS_SUMS + 9)
#define WS_MEDIAN   (WS_SUMS + 10)
// total ~4.99M floats (~20 MB)

__device__ __forceinline__ void block_sum_atomic(float v, float* dst){
  #pragma unroll
  for (int o = 32; o > 0; o >>= 1) v += __shfl_down(v, o, 64);
  __shared__ float red[4];
  int lane = threadIdx.x & 63, wid = threadIdx.x >> 6;
  if (lane == 0) red[wid] = v;
  __syncthreads();
  if (threadIdx.x == 0) atomicAdd(dst, red[0] + red[1] + red[2] + red[3]);
}

// ---------------- setup: downsampled illum & sens ----------------
__global__ __launch_bounds__(256) void k_setup(const float* __restrict__ illum,
                                               const float* __restrict__ sens,
                                               float* __restrict__ ws){
  int pix = blockIdx.x * 256 + threadIdx.x;
  int i = pix >> 8, j = pix & 255;
  float si = 0.f, ss = 0.f;
  #pragma unroll
  for (int p = 0; p < 3; p++)
    #pragma unroll
    for (int q = 0; q < 3; q++){
      float se = sens[(3*i+p)*FW + 3*j+q];
      float il = illum[(3*i+p)*FW + 3*j+q];
      si = fmaf(se, il * 0.125f, si);
      ss += se;
    }
  ws[WS_ILLUM + pix] = si;
  ws[WS_SENS  + pix] = ss * (1.f/9.f);
}

// ---------------- weight transpose ----------------
__global__ void k_wt(const float* __restrict__ w1, const float* __restrict__ w2,
                     const float* __restrict__ w3, float* __restrict__ ws){
  int t = threadIdx.x;
  for (int idx = t; idx < 288; idx += 256){
    int co = idx / 9, k = idx % 9;
    ws[WS_W1T + k*32 + co] = w1[idx];
  }
  for (int idx = t; idx < 9216; idx += 256){
    int co = idx / 288, ci = (idx / 9) % 32, k = idx % 9;
    ws[WS_W2T + (ci*9 + k)*32 + co] = w2[idx];
  }
  for (int idx = t; idx < 3456; idx += 256){
    int co = idx / 288, ci = (idx / 9) % 32, k = idx % 9;
    ws[WS_W3T + (ci*9 + k)*12 + co] = w3[idx];
  }
}

// ---------------- bias stats: mean + median (radix select) ----------------
__global__ __launch_bounds__(1024) void k_stats(const float* __restrict__ bias,
                                                float* __restrict__ ws){
  __shared__ float sred[1024];
  __shared__ unsigned hist[256];
  __shared__ unsigned s_prefix, s_k;
  int t = threadIdx.x;

  float s = 0.f;
  for (int i = t; i < N2; i += 1024) s += bias[i];
  sred[t] = s; __syncthreads();
  for (int w = 512; w > 0; w >>= 1){ if (t < w) sred[t] += sred[t+w]; __syncthreads(); }
  if (t == 0) ws[WS_MEANB] = sred[0] * (1.f / N2);

  float med[2];
  for (int sel = 0; sel < 2; sel++){
    unsigned k = 32767u + (unsigned)sel;   // 0-indexed target
    unsigned prefix = 0;
    for (int pass = 0; pass < 4; pass++){
      int shift = 24 - 8*pass;
      unsigned pmask = (pass == 0) ? 0u : (0xFFFFFFFFu << (32 - 8*pass));
      if (t < 256) hist[t] = 0;
      __syncthreads();
      for (int i = t; i < N2; i += 1024){
        unsigned u = __float_as_uint(bias[i]);
        unsigned key = (u & 0x80000000u) ? ~u : (u ^ 0x80000000u);
        if ((key & pmask) == prefix) atomicAdd(&hist[(key >> shift) & 255u], 1u);
      }
      __syncthreads();
      if (t == 0){
        unsigned cum = 0, b = 0;
        for (; b < 256; b++){ unsigned c = hist[b]; if (cum + c > k) break; cum += c; }
        s_prefix = prefix | (b << shift);
        s_k = k - cum;
      }
      __syncthreads();
      prefix = s_prefix; k = s_k;
      __syncthreads();
    }
    unsigned key = prefix;
    unsigned u = (key & 0x80000000u) ? (key ^ 0x80000000u) : ~key;
    med[sel] = __uint_as_float(u);
  }
  if (t == 0){
    ws[WS_MEDIAN] = 0.5f * (med[0] + med[1]);
    #pragma unroll
    for (int i = 0; i < 9; i++) ws[WS_SUMS + i] = 0.f;
  }
}

// ---------------- init charge, ramp[0], sums[0] ----------------
__global__ __launch_bounds__(256) void k_init(const float* __restrict__ bias,
                                              float* __restrict__ ws,
                                              float* __restrict__ out){
  int pix = blockIdx.x * 256 + threadIdx.x;
  float meanb = ws[WS_MEANB], med = ws[WS_MEDIAN];
  float c = bias[pix] - meanb;
  ws[WS_CHARGE + pix] = c;
  out[pix] = c + med;
  block_sum_atomic(c, ws + WS_SUMS + 0);
}

// ---------------- conv1: 1 -> 32, 3x3 SAME, relu ----------------
__global__ __launch_bounds__(256) void k_conv1(float* __restrict__ ws, int step){
  __shared__ float tile[18*18];
  const float* charge = ws + WS_CHARGE;
  const float* w = ws + WS_W1T;
  float mean = ws[WS_SUMS + step] * (1.f / N2);
  int gi0 = (blockIdx.x >> 4) * 16, gj0 = (blockIdx.x & 15) * 16;
  for (int idx = threadIdx.x; idx < 324; idx += 256){
    int r = idx / 18, c = idx % 18;
    int gi = gi0 + r - 1, gj = gj0 + c - 1;
    float v = 0.f;
    if ((unsigned)gi < 256u && (unsigned)gj < 256u) v = charge[gi*256 + gj] - mean;
    tile[idx] = v;
  }
  __syncthreads();
  int ti = threadIdx.x >> 4, tj = threadIdx.x & 15;
  float x[9];
  #pragma unroll
  for (int dy = 0; dy < 3; dy++)
    #pragma unroll
    for (int dx = 0; dx < 3; dx++) x[dy*3+dx] = tile[(ti+dy)*18 + tj+dx];
  float acc[32];
  #pragma unroll
  for (int co = 0; co < 32; co++) acc[co] = 0.f;
  #pragma unroll
  for (int k = 0; k < 9; k++){
    const float* wp = w + k*32;
    #pragma unroll
    for (int co = 0; co < 32; co++) acc[co] = fmaf(wp[co], x[k], acc[co]);
  }
  int pix = (gi0 + ti)*256 + gj0 + tj;
  float* f1 = ws + WS_FEAT1;
  #pragma unroll
  for (int co = 0; co < 32; co++) f1[co*N2 + pix] = fmaxf(acc[co], 0.f);
}

// ---------------- conv2: 32 -> 32, 3x3 SAME, relu ----------------
__global__ __launch_bounds__(256) void k_conv2(float* __restrict__ ws){
  __shared__ float tile[32*324];
  const float* f1 = ws + WS_FEAT1;
  const float* w = ws + WS_W2T;
  int gi0 = (blockIdx.x >> 4) * 16, gj0 = (blockIdx.x & 15) * 16;
  for (int idx = threadIdx.x; idx < 32*324; idx += 256){
    int ci = idx / 324, rem = idx % 324, r = rem / 18, c = rem % 18;
    int gi = gi0 + r - 1, gj = gj0 + c - 1;
    float v = 0.f;
    if ((unsigned)gi < 256u && (unsigned)gj < 256u) v = f1[ci*N2 + gi*256 + gj];
    tile[idx] = v;
  }
  __syncthreads();
  int ti = threadIdx.x >> 4, tj = threadIdx.x & 15;
  float acc[32];
  #pragma unroll
  for (int co = 0; co < 32; co++) acc[co] = 0.f;
  for (int ci = 0; ci < 32; ci++){
    float x[9];
    #pragma unroll
    for (int dy = 0; dy < 3; dy++)
      #pragma unroll
      for (int dx = 0; dx < 3; dx++) x[dy*3+dx] = tile[ci*324 + (ti+dy)*18 + tj+dx];
    #pragma unroll
    for (int k = 0; k < 9; k++){
      const float* wp = w + (ci*9 + k)*32;
      #pragma unroll
      for (int co = 0; co < 32; co++) acc[co] = fmaf(wp[co], x[k], acc[co]);
    }
  }
  int pix = (gi0 + ti)*256 + gj0 + tj;
  float* f2 = ws + WS_FEAT2;
  #pragma unroll
  for (int co = 0; co < 32; co++) f2[co*N2 + pix] = fmaxf(acc[co], 0.f);
}

// ------- conv3: 32 -> 12 (coeffs), fused coords/overlap -> S planes -------
__global__ __launch_bounds__(256) void k_conv3(float* __restrict__ ws,
                                               const float* __restrict__ illum){
  __shared__ float tile[32*324];
  const float* f2 = ws + WS_FEAT2;
  const float* w = ws + WS_W3T;
  int gi0 = (blockIdx.x >> 4) * 16, gj0 = (blockIdx.x & 15) * 16;
  for (int idx = threadIdx.x; idx < 32*324; idx += 256){
    int ci = idx / 324, rem = idx % 324, r = rem / 18, c = rem % 18;
    int gi = gi0 + r - 1, gj = gj0 + c - 1;
    float v = 0.f;
    if ((unsigned)gi < 256u && (unsigned)gj < 256u) v = f2[ci*N2 + gi*256 + gj];
    tile[idx] = v;
  }
  __syncthreads();
  int ti = threadIdx.x >> 4, tj = threadIdx.x & 15;
  float acc[12];
  #pragma unroll
  for (int co = 0; co < 12; co++) acc[co] = 0.f;
  for (int ci = 0; ci < 32; ci++){
    float x[9];
    #pragma unroll
    for (int dy = 0; dy < 3; dy++)
      #pragma unroll
      for (int dx = 0; dx < 3; dx++) x[dy*3+dx] = tile[ci*324 + (ti+dy)*18 + tj+dx];
    #pragma unroll
    for (int k = 0; k < 9; k++){
      const float* wp = w + (ci*9 + k)*12;
      #pragma unroll
      for (int co = 0; co < 12; co++) acc[co] = fmaf(wp[co], x[k], acc[co]);
    }
  }
  // epilogue: per-pixel coords -> overlap fractions -> S[du,dv]
  int i = gi0 + ti, j = gj0 + tj;
  float S[9];
  #pragma unroll
  for (int d = 0; d < 9; d++) S[d] = 0.f;
  const float third = 1.f/3.f, sixth = 1.f/6.f;
  #pragma unroll
  for (int p = 0; p < 3; p++){
    float kx = (p - 1) * third;
    #pragma unroll
    for (int q = 0; q < 3; q++){
      float ky = (q - 1) * third;
      // coeffs order: (0,0),(0,1),(1,0),(0,2),(1,1),(2,0) on (px,py)
      float cx = kx + acc[0] + acc[1]*ky + acc[2]*kx + acc[3]*ky*ky + acc[4]*kx*ky + acc[5]*kx*kx;
      float cy = ky + acc[6] + acc[7]*ky + acc[8]*kx + acc[9]*ky*ky + acc[10]*kx*ky + acc[11]*kx*kx;
      float Ipq = illum[(3*i+p)*FW + 3*j+q] * 0.125f;
      float ox[3], oy[3];
      #pragma unroll
      for (int d = 0; d < 3; d++){
        float xx = cx + (float)(d - 1);
        ox[d] = fmaxf(0.f, fminf(xx + sixth, 0.5f) - fmaxf(xx - sixth, -0.5f));
        float yy = cy + (float)(d - 1);
        oy[d] = fmaxf(0.f, fminf(yy + sixth, 0.5f) - fmaxf(yy - sixth, -0.5f));
      }
      #pragma unroll
      for (int d = 0; d < 3; d++){
        float a = Ipq * ox[d];
        #pragma unroll
        for (int e = 0; e < 3; e++) S[d*3+e] = fmaf(a, oy[e], S[d*3+e]);
      }
    }
  }
  int pix = i*256 + j;
  float* Sp = ws + WS_S;
  #pragma unroll
  for (int d = 0; d < 9; d++) Sp[d*N2 + pix] = S[d];
}

// ------- apply: 9-point stencil on S, charge update, outputs, next mean -------
__global__ __launch_bounds__(256) void k_apply(float* __restrict__ ws,
                                               float* __restrict__ out, int step){
  int pix = blockIdx.x * 256 + threadIdx.x;
  int i = pix >> 8, j = pix & 255;
  const float* Sp = ws + WS_S;
  float s = 0.f;
  #pragma unroll
  for (int d = 0; d < 3; d++)
    #pragma unroll
    for (int e = 0; e < 3; e++){
      int a = i + d - 1, b = j + e - 1;
      if ((unsigned)a < 256u && (unsigned)b < 256u)
        s += Sp[(d*3 + e)*N2 + a*256 + b];
    }
  float nc = ws[WS_SENS + pix] * (9.f * s);
  float ch = ws[WS_CHARGE + pix] + nc;
  ws[WS_CHARGE + pix] = ch;
  float med = ws[WS_MEDIAN];
  out[(step + 1)*N2 + pix] = ch + med;          // ramp[t+1]
  out[(9 + step)*N2 + pix] = ws[WS_ILLUM + pix] - nc;  // diffusions[t]
  block_sum_atomic(ch, ws + WS_SUMS + step + 1);
}

extern "C" void kernel_launch(void* const* d_in, const int* in_sizes, int n_in,
                              void* d_out, int out_size, void* d_ws, size_t ws_size,
                              hipStream_t stream) {
  (void)in_sizes; (void)n_in; (void)out_size; (void)ws_size;
  const float* bias  = (const float*)d_in[0];
  const float* illum = (const float*)d_in[1];
  const float* sens  = (const float*)d_in[2];
  const float* w1    = (const float*)d_in[3];
  const float* w2    = (const float*)d_in[4];
  const float* w3    = (const float*)d_in[5];
  float* out = (float*)d_out;
  float* ws  = (float*)d_ws;

  k_setup<<<256, 256, 0, stream>>>(illum, sens, ws);
  k_wt   <<<1,   256, 0, stream>>>(w1, w2, w3, ws);
  k_stats<<<1,  1024, 0, stream>>>(bias, ws);
  k_init <<<256, 256, 0, stream>>>(bias, ws, out);
  for (int t = 0; t < 8; t++){
    k_conv1<<<256, 256, 0, stream>>>(ws, t);
    k_conv2<<<256, 256, 0, stream>>>(ws);
    k_conv3<<<256, 256, 0, stream>>>(ws, illum);
    k_apply<<<256, 256, 0, stream>>>(ws, out, t);
  }
}

// Round 2
// 758.716 us; speedup vs baseline: 1.6367x; 1.6367x over previous
//
#include <hip/hip_runtime.h>

#define NPIX 256
#define N2   65536
#define FW   768

// ---------------- workspace layout (float offsets) ----------------
#define WS_CHARGE   0
#define WS_ILLUM    (N2)
#define WS_SENS     (2*N2)
#define WS_FEAT2    (3*N2)               // 32 x 256 x 256, CHW
#define WS_S        (35*N2)              // 9 planes of 256x256
#define WS_W1T      (44*N2)              // [k][co]            288
#define WS_W2T      (WS_W1T + 288)       // [(ci*9+k)*32+co]   9216
#define WS_W3T      (WS_W2T + 9216)      // [(ci*9+k)*12+co]   3456
#define WS_ZB       (WS_W3T + 3456)      // zeroed region base (16B aligned)
#define WS_SUMS     (WS_ZB)              // 9 charge sums
#define WS_BSUM     (WS_ZB + 9)
#define WS_MEANB    (WS_ZB + 10)
#define WS_MEDIAN   (WS_ZB + 11)
#define WS_SEL      (WS_ZB + 12)         // 4 uints: prefix0,k0,prefix1,k1
#define WS_HIST1    (WS_ZB + 32)         // 65536 u32
#define WS_HIST2    (WS_HIST1 + 65536)   // 2*65536 u32
#define NZERO_F     (32 + 65536 + 131072)

__device__ __forceinline__ void block_sum_atomic(float v, float* dst){
  #pragma unroll
  for (int o = 32; o > 0; o >>= 1) v += __shfl_down(v, o, 64);
  __shared__ float red[4];
  int lane = threadIdx.x & 63, wid = threadIdx.x >> 6;
  if (lane == 0) red[wid] = v;
  __syncthreads();
  if (threadIdx.x == 0){
    float s = red[0];
    for (int w = 1; w < (int)(blockDim.x >> 6); w++) s += red[w];
    atomicAdd(dst, s);
  }
}

// ---------------- clear the histogram / accumulator region ----------------
__global__ __launch_bounds__(256) void k_clear(float* __restrict__ ws){
  uint4* p = (uint4*)(ws + WS_ZB);
  int n = NZERO_F / 4;
  for (int i = blockIdx.x * 256 + threadIdx.x; i < n; i += gridDim.x * 256)
    p[i] = make_uint4(0u, 0u, 0u, 0u);
}

// ---------------- setup: downsampled illum & sens ----------------
__global__ __launch_bounds__(256) void k_setup(const float* __restrict__ illum,
                                               const float* __restrict__ sens,
                                               float* __restrict__ ws){
  int pix = blockIdx.x * 256 + threadIdx.x;
  int i = pix >> 8, j = pix & 255;
  float si = 0.f, ss = 0.f;
  #pragma unroll
  for (int p = 0; p < 3; p++)
    #pragma unroll
    for (int q = 0; q < 3; q++){
      float se = sens[(3*i+p)*FW + 3*j+q];
      float il = illum[(3*i+p)*FW + 3*j+q];
      si = fmaf(se, il * 0.125f, si);
      ss += se;
    }
  ws[WS_ILLUM + pix] = si;
  ws[WS_SENS  + pix] = ss * (1.f/9.f);
}

// ---------------- weight transpose ----------------
__global__ void k_wt(const float* __restrict__ w1, const float* __restrict__ w2,
                     const float* __restrict__ w3, float* __restrict__ ws){
  int t = threadIdx.x;
  for (int idx = t; idx < 288; idx += 256){
    int co = idx / 9, k = idx % 9;
    ws[WS_W1T + k*32 + co] = w1[idx];
  }
  for (int idx = t; idx < 9216; idx += 256){
    int co = idx / 288, ci = (idx / 9) % 32, k = idx % 9;
    ws[WS_W2T + (ci*9 + k)*32 + co] = w2[idx];
  }
  for (int idx = t; idx < 3456; idx += 256){
    int co = idx / 288, ci = (idx / 9) % 32, k = idx % 9;
    ws[WS_W3T + (ci*9 + k)*12 + co] = w3[idx];
  }
}

// ---------------- histogram of top-16 bits + bias sum ----------------
__global__ __launch_bounds__(256) void k_hist1(const float* __restrict__ bias,
                                               float* __restrict__ ws){
  unsigned* hist = (unsigned*)(ws + WS_HIST1);
  float s = 0.f;
  for (int i = blockIdx.x * 256 + threadIdx.x; i < N2; i += gridDim.x * 256){
    float v = bias[i]; s += v;
    unsigned u = __float_as_uint(v);
    unsigned key = (u & 0x80000000u) ? ~u : (u ^ 0x80000000u);
    atomicAdd(&hist[key >> 16], 1u);
  }
  block_sum_atomic(s, ws + WS_BSUM);
}

// ---------------- scan hist1: find 16-bit prefixes for ranks 32767/32768 ----------------
__global__ __launch_bounds__(256) void k_med1(float* __restrict__ ws){
  const unsigned* hist = (const unsigned*)(ws + WS_HIST1);
  unsigned* sel = (unsigned*)(ws + WS_SEL);
  __shared__ unsigned cnt[256], cum[256];
  int t = threadIdx.x;
  const uint4* h4 = (const uint4*)hist + t*64;
  unsigned c = 0;
  #pragma unroll 8
  for (int j = 0; j < 64; j++){ uint4 v = h4[j]; c += v.x + v.y + v.z + v.w; }
  cnt[t] = c; cum[t] = c;
  __syncthreads();
  for (int off = 1; off < 256; off <<= 1){
    unsigned a = (t >= off) ? cum[t - off] : 0u;
    __syncthreads();
    cum[t] += a;
    __syncthreads();
  }
  unsigned before = cum[t] - cnt[t];
  for (int s = 0; s < 2; s++){
    unsigned rank = 32767u + (unsigned)s;
    if (before <= rank && rank < cum[t]){
      unsigned k = rank - before, acc = 0; int b = 0;
      for (; b < 256; b++){ unsigned h = hist[t*256 + b]; if (acc + h > k) break; acc += h; }
      sel[s*2]     = (unsigned)(t*256 + b);
      sel[s*2 + 1] = k - acc;
    }
  }
}

// ---------------- gated low-16 histograms ----------------
__global__ __launch_bounds__(256) void k_hist2(const float* __restrict__ bias,
                                               float* __restrict__ ws){
  const unsigned* sel = (const unsigned*)(ws + WS_SEL);
  unsigned* h2 = (unsigned*)(ws + WS_HIST2);
  unsigned p0 = sel[0], p1 = sel[2];
  for (int i = blockIdx.x * 256 + threadIdx.x; i < N2; i += gridDim.x * 256){
    unsigned u = __float_as_uint(bias[i]);
    unsigned key = (u & 0x80000000u) ? ~u : (u ^ 0x80000000u);
    unsigned top = key >> 16;
    if (top == p0) atomicAdd(&h2[key & 0xFFFFu], 1u);
    if (top == p1) atomicAdd(&h2[65536 + (key & 0xFFFFu)], 1u);
  }
}

// ---------------- scan hist2: exact median; finalize mean ----------------
__global__ __launch_bounds__(256) void k_med2(float* __restrict__ ws){
  const unsigned* sel = (const unsigned*)(ws + WS_SEL);
  __shared__ unsigned cnt[256], cum[256];
  __shared__ float meds[2];
  int t = threadIdx.x;
  for (int s = 0; s < 2; s++){
    const unsigned* h = (const unsigned*)(ws + WS_HIST2) + s*65536;
    const uint4* h4 = (const uint4*)h + t*64;
    unsigned c = 0;
    #pragma unroll 8
    for (int j = 0; j < 64; j++){ uint4 v = h4[j]; c += v.x + v.y + v.z + v.w; }
    cnt[t] = c; cum[t] = c;
    __syncthreads();
    for (int off = 1; off < 256; off <<= 1){
      unsigned a = (t >= off) ? cum[t - off] : 0u;
      __syncthreads();
      cum[t] += a;
      __syncthreads();
    }
    unsigned rank = sel[s*2 + 1];
    unsigned before = cum[t] - cnt[t];
    if (before <= rank && rank < cum[t]){
      unsigned k = rank - before, acc = 0; int b = 0;
      for (; b < 256; b++){ unsigned hh = h[t*256 + b]; if (acc + hh > k) break; acc += hh; }
      unsigned key = (sel[s*2] << 16) | (unsigned)(t*256 + b);
      unsigned u = (key & 0x80000000u) ? (key ^ 0x80000000u) : ~key;
      meds[s] = __uint_as_float(u);
    }
    __syncthreads();
  }
  if (t == 0){
    ws[WS_MEDIAN] = 0.5f * (meds[0] + meds[1]);
    ws[WS_MEANB]  = ws[WS_BSUM] * (1.f / N2);
  }
}

// ---------------- init charge, ramp[0], sums[0] ----------------
__global__ __launch_bounds__(256) void k_init(const float* __restrict__ bias,
                                              float* __restrict__ ws,
                                              float* __restrict__ out){
  int pix = blockIdx.x * 256 + threadIdx.x;
  float meanb = ws[WS_MEANB], med = ws[WS_MEDIAN];
  float c = bias[pix] - meanb;
  ws[WS_CHARGE + pix] = c;
  out[pix] = c + med;
  block_sum_atomic(c, ws + WS_SUMS + 0);
}

// ------- convA: fused conv1(1->32) + conv2(32->32), relu, feat2 to global -------
// 256 blocks (16x16 px tiles), 256 threads. conv2 is co-split across the 4 waves:
// wave w owns co [8w,8w+8); each lane computes 4 consecutive px (row=lane>>2,
// cols=(lane&3)*4 ..+3). Weights via uniform float4 global loads (L1 broadcast),
// f1 in LDS padded [32][18][20] so x-window reads are aligned b128+b64.
__global__ __launch_bounds__(256) void k_convA(float* __restrict__ ws,
                                               const float* __restrict__ w1t,
                                               const float* __restrict__ w2t,
                                               int step){
  __shared__ float chg[400];        // 20x20 charge tile (halo 2)
  __shared__ float f1[32*360];      // [ci][18 rows][20 cols padded]
  const float* charge = ws + WS_CHARGE;
  float mean = ws[WS_SUMS + step] * (1.f / N2);
  int gi0 = (blockIdx.x >> 4) * 16, gj0 = (blockIdx.x & 15) * 16;
  int tid = threadIdx.x;

  for (int idx = tid; idx < 400; idx += 256){
    int r = idx / 20, c = idx % 20;
    int gi = gi0 + r - 2, gj = gj0 + c - 2;
    float v = 0.f;
    if ((unsigned)gi < 256u && (unsigned)gj < 256u) v = charge[gi*256 + gj] - mean;
    chg[idx] = v;
  }
  __syncthreads();

  // conv1 on the 18x18 f1 tile; zero for positions outside the image
  for (int idx = tid; idx < 324; idx += 256){
    int r = idx / 18, c = idx % 18;
    int gi = gi0 + r - 1, gj = gj0 + c - 1;
    float acc[32];
    #pragma unroll
    for (int co = 0; co < 32; co++) acc[co] = 0.f;
    if ((unsigned)gi < 256u && (unsigned)gj < 256u){
      float x[9];
      #pragma unroll
      for (int dy = 0; dy < 3; dy++)
        #pragma unroll
        for (int dx = 0; dx < 3; dx++) x[dy*3+dx] = chg[(r+dy)*20 + c+dx];
      #pragma unroll
      for (int k = 0; k < 9; k++){
        float xv = x[k];
        const float4* wr = (const float4*)(w1t + k*32);
        #pragma unroll
        for (int g = 0; g < 8; g++){
          float4 w4 = wr[g];
          acc[g*4+0] = fmaf(w4.x, xv, acc[g*4+0]);
          acc[g*4+1] = fmaf(w4.y, xv, acc[g*4+1]);
          acc[g*4+2] = fmaf(w4.z, xv, acc[g*4+2]);
          acc[g*4+3] = fmaf(w4.w, xv, acc[g*4+3]);
        }
      }
      #pragma unroll
      for (int co = 0; co < 32; co++) acc[co] = fmaxf(acc[co], 0.f);
    }
    #pragma unroll
    for (int co = 0; co < 32; co++) f1[co*360 + r*20 + c] = acc[co];
  }
  __syncthreads();

  // conv2, co-split
  int wv = tid >> 6, lane = tid & 63;
  int co8 = wv * 8;
  int ti = lane >> 2, tjq = (lane & 3) * 4;
  float acc[4][8];
  #pragma unroll
  for (int p = 0; p < 4; p++)
    #pragma unroll
    for (int c = 0; c < 8; c++) acc[p][c] = 0.f;

  for (int ci = 0; ci < 32; ci++){
    float xr[3][6];
    #pragma unroll
    for (int dy = 0; dy < 3; dy++){
      const float* rp = f1 + ci*360 + (ti+dy)*20 + tjq;
      float4 a = *(const float4*)rp;
      float2 b = *(const float2*)(rp + 4);
      xr[dy][0] = a.x; xr[dy][1] = a.y; xr[dy][2] = a.z; xr[dy][3] = a.w;
      xr[dy][4] = b.x; xr[dy][5] = b.y;
    }
    #pragma unroll
    for (int k = 0; k < 9; k++){
      int dy = k / 3, dx = k % 3;
      const float4* wrow = (const float4*)(w2t + (ci*9 + k)*32 + co8);
      float4 wa = wrow[0], wb = wrow[1];
      #pragma unroll
      for (int p = 0; p < 4; p++){
        float xv = xr[dy][p + dx];
        acc[p][0] = fmaf(wa.x, xv, acc[p][0]);
        acc[p][1] = fmaf(wa.y, xv, acc[p][1]);
        acc[p][2] = fmaf(wa.z, xv, acc[p][2]);
        acc[p][3] = fmaf(wa.w, xv, acc[p][3]);
        acc[p][4] = fmaf(wb.x, xv, acc[p][4]);
        acc[p][5] = fmaf(wb.y, xv, acc[p][5]);
        acc[p][6] = fmaf(wb.z, xv, acc[p][6]);
        acc[p][7] = fmaf(wb.w, xv, acc[p][7]);
      }
    }
  }
  float* f2 = ws + WS_FEAT2;
  int prow = (gi0 + ti)*256 + gj0 + tjq;
  #pragma unroll
  for (int co = 0; co < 8; co++){
    float4 v;
    v.x = fmaxf(acc[0][co], 0.f);
    v.y = fmaxf(acc[1][co], 0.f);
    v.z = fmaxf(acc[2][co], 0.f);
    v.w = fmaxf(acc[3][co], 0.f);
    *(float4*)(f2 + (co8 + co)*N2 + prow) = v;
  }
}

// ------- convB: conv3 (32->12) + distortion/overlap epilogue -> S planes -------
__global__ __launch_bounds__(256) void k_convB(float* __restrict__ ws,
                                               const float* __restrict__ w3t,
                                               const float* __restrict__ illum){
  __shared__ float tile[32*324];
  const float* f2 = ws + WS_FEAT2;
  int gi0 = (blockIdx.x >> 4) * 16, gj0 = (blockIdx.x & 15) * 16;
  for (int idx = threadIdx.x; idx < 32*324; idx += 256){
    int ci = idx / 324, rem = idx % 324, r = rem / 18, c = rem % 18;
    int gi = gi0 + r - 1, gj = gj0 + c - 1;
    float v = 0.f;
    if ((unsigned)gi < 256u && (unsigned)gj < 256u) v = f2[ci*N2 + gi*256 + gj];
    tile[idx] = v;
  }
  __syncthreads();
  int ti = threadIdx.x >> 4, tj = threadIdx.x & 15;
  float acc[12];
  #pragma unroll
  for (int co = 0; co < 12; co++) acc[co] = 0.f;
  for (int ci = 0; ci < 32; ci++){
    float x[9];
    #pragma unroll
    for (int dy = 0; dy < 3; dy++)
      #pragma unroll
      for (int dx = 0; dx < 3; dx++) x[dy*3+dx] = tile[ci*324 + (ti+dy)*18 + tj+dx];
    #pragma unroll
    for (int k = 0; k < 9; k++){
      const float4* wr = (const float4*)(w3t + (ci*9 + k)*12);
      float4 a = wr[0], b = wr[1], c4 = wr[2];
      float xv = x[k];
      acc[0] = fmaf(a.x, xv, acc[0]);  acc[1] = fmaf(a.y, xv, acc[1]);
      acc[2] = fmaf(a.z, xv, acc[2]);  acc[3] = fmaf(a.w, xv, acc[3]);
      acc[4] = fmaf(b.x, xv, acc[4]);  acc[5] = fmaf(b.y, xv, acc[5]);
      acc[6] = fmaf(b.z, xv, acc[6]);  acc[7] = fmaf(b.w, xv, acc[7]);
      acc[8] = fmaf(c4.x, xv, acc[8]); acc[9] = fmaf(c4.y, xv, acc[9]);
      acc[10] = fmaf(c4.z, xv, acc[10]); acc[11] = fmaf(c4.w, xv, acc[11]);
    }
  }
  int i = gi0 + ti, j = gj0 + tj;
  float S[9];
  #pragma unroll
  for (int d = 0; d < 9; d++) S[d] = 0.f;
  const float third = 1.f/3.f, sixth = 1.f/6.f;
  #pragma unroll
  for (int p = 0; p < 3; p++){
    float kx = (p - 1) * third;
    #pragma unroll
    for (int q = 0; q < 3; q++){
      float ky = (q - 1) * third;
      float cx = kx + acc[0] + acc[1]*ky + acc[2]*kx + acc[3]*ky*ky + acc[4]*kx*ky + acc[5]*kx*kx;
      float cy = ky + acc[6] + acc[7]*ky + acc[8]*kx + acc[9]*ky*ky + acc[10]*kx*ky + acc[11]*kx*kx;
      float Ipq = illum[(3*i+p)*FW + 3*j+q] * 0.125f;
      float ox[3], oy[3];
      #pragma unroll
      for (int d = 0; d < 3; d++){
        float xx = cx + (float)(d - 1);
        ox[d] = fmaxf(0.f, fminf(xx + sixth, 0.5f) - fmaxf(xx - sixth, -0.5f));
        float yy = cy + (float)(d - 1);
        oy[d] = fmaxf(0.f, fminf(yy + sixth, 0.5f) - fmaxf(yy - sixth, -0.5f));
      }
      #pragma unroll
      for (int d = 0; d < 3; d++){
        float a = Ipq * ox[d];
        #pragma unroll
        for (int e = 0; e < 3; e++) S[d*3+e] = fmaf(a, oy[e], S[d*3+e]);
      }
    }
  }
  int pix = i*256 + j;
  float* Sp = ws + WS_S;
  #pragma unroll
  for (int d = 0; d < 9; d++) Sp[d*N2 + pix] = S[d];
}

// ------- apply: 9-point stencil on S, charge update, outputs, next mean -------
__global__ __launch_bounds__(256) void k_apply(float* __restrict__ ws,
                                               float* __restrict__ out, int step){
  int pix = blockIdx.x * 256 + threadIdx.x;
  int i = pix >> 8, j = pix & 255;
  const float* Sp = ws + WS_S;
  float s = 0.f;
  #pragma unroll
  for (int d = 0; d < 3; d++)
    #pragma unroll
    for (int e = 0; e < 3; e++){
      int a = i + d - 1, b = j + e - 1;
      if ((unsigned)a < 256u && (unsigned)b < 256u)
        s += Sp[(d*3 + e)*N2 + a*256 + b];
    }
  float nc = ws[WS_SENS + pix] * (9.f * s);
  float ch = ws[WS_CHARGE + pix] + nc;
  ws[WS_CHARGE + pix] = ch;
  float med = ws[WS_MEDIAN];
  out[(step + 1)*N2 + pix] = ch + med;
  out[(9 + step)*N2 + pix] = ws[WS_ILLUM + pix] - nc;
  block_sum_atomic(ch, ws + WS_SUMS + step + 1);
}

extern "C" void kernel_launch(void* const* d_in, const int* in_sizes, int n_in,
                              void* d_out, int out_size, void* d_ws, size_t ws_size,
                              hipStream_t stream) {
  (void)in_sizes; (void)n_in; (void)out_size; (void)ws_size;
  const float* bias  = (const float*)d_in[0];
  const float* illum = (const float*)d_in[1];
  const float* sens  = (const float*)d_in[2];
  const float* w1    = (const float*)d_in[3];
  const float* w2    = (const float*)d_in[4];
  const float* w3    = (const float*)d_in[5];
  float* out = (float*)d_out;
  float* ws  = (float*)d_ws;
  const float* w1t = ws + WS_W1T;
  const float* w2t = ws + WS_W2T;
  const float* w3t = ws + WS_W3T;

  k_clear<<<128, 256, 0, stream>>>(ws);
  k_setup<<<256, 256, 0, stream>>>(illum, sens, ws);
  k_wt   <<<1,   256, 0, stream>>>(w1, w2, w3, ws);
  k_hist1<<<64,  256, 0, stream>>>(bias, ws);
  k_med1 <<<1,   256, 0, stream>>>(ws);
  k_hist2<<<64,  256, 0, stream>>>(bias, ws);
  k_med2 <<<1,   256, 0, stream>>>(ws);
  k_init <<<256, 256, 0, stream>>>(bias, ws, out);
  for (int t = 0; t < 8; t++){
    k_convA<<<256, 256, 0, stream>>>(ws, w1t, w2t, t);
    k_convB<<<256, 256, 0, stream>>>(ws, w3t, illum);
    k_apply<<<256, 256, 0, stream>>>(ws, out, t);
  }
}